// Round 2
// baseline (2452.164 us; speedup 1.0000x reference)
//
#include <hip/hip_runtime.h>

#define NN 100000
#define NE 600000
#define DIM 128
#define NG 256

// ---------------- embed + layernorm (wave per node) ----------------
__global__ __launch_bounds__(256) void embed_ln_kernel(
    const int* __restrict__ x_idx, const float* __restrict__ emb,
    const float* __restrict__ g, const float* __restrict__ b,
    float* __restrict__ out) {
  int wave = threadIdx.x >> 6;
  int lane = threadIdx.x & 63;
  int n = blockIdx.x * 4 + wave;
  if (n >= NN) return;
  int idx = x_idx[n];
  float2 v = ((const float2*)(emb + (size_t)idx * DIM))[lane];
  float s = v.x + v.y;
  float sq = v.x * v.x + v.y * v.y;
  for (int off = 32; off; off >>= 1) {
    s += __shfl_xor(s, off);
    sq += __shfl_xor(sq, off);
  }
  float m = s * (1.0f / 128.0f);
  float var = sq * (1.0f / 128.0f) - m * m;
  float r = rsqrtf(var + 1e-5f);
  float2 gg = ((const float2*)g)[lane];
  float2 bb = ((const float2*)b)[lane];
  float2 o;
  o.x = (v.x - m) * r * gg.x + bb.x;
  o.y = (v.y - m) * r * gg.y + bb.y;
  ((float2*)(out + (size_t)n * DIM))[lane] = o;
}

// ---------------- layernorm from buffer ----------------
__global__ __launch_bounds__(256) void ln_kernel(
    const float* __restrict__ in, const float* __restrict__ g,
    const float* __restrict__ b, float* __restrict__ out) {
  int wave = threadIdx.x >> 6;
  int lane = threadIdx.x & 63;
  int n = blockIdx.x * 4 + wave;
  if (n >= NN) return;
  float2 v = ((const float2*)(in + (size_t)n * DIM))[lane];
  float s = v.x + v.y;
  float sq = v.x * v.x + v.y * v.y;
  for (int off = 32; off; off >>= 1) {
    s += __shfl_xor(s, off);
    sq += __shfl_xor(sq, off);
  }
  float m = s * (1.0f / 128.0f);
  float var = sq * (1.0f / 128.0f) - m * m;
  float r = rsqrtf(var + 1e-5f);
  float2 gg = ((const float2*)g)[lane];
  float2 bb = ((const float2*)b)[lane];
  float2 o;
  o.x = (v.x - m) * r * gg.x + bb.x;
  o.y = (v.y - m) * r * gg.y + bb.y;
  ((float2*)(out + (size_t)n * DIM))[lane] = o;
}

// ---------------- degree count ----------------
__global__ __launch_bounds__(256) void deg_kernel(const int* __restrict__ dst,
                                                  float* __restrict__ deg) {
  int e = blockIdx.x * 256 + threadIdx.x;
  if (e < NE) atomicAdd(deg + dst[e], 1.0f);
}

// ---------------- edge scatter: agg[dst] += x[src] ----------------
__global__ __launch_bounds__(256) void scatter_kernel(
    const int* __restrict__ src, const int* __restrict__ dst,
    const float* __restrict__ x, float* __restrict__ agg) {
  int t = blockIdx.x * 256 + threadIdx.x;
  int e = t >> 5;
  int q = t & 31;
  if (e >= NE) return;
  int s = src[e], d = dst[e];
  float4 v = ((const float4*)(x + (size_t)s * DIM))[q];
  float* p = agg + (size_t)d * DIM + q * 4;
  atomicAdd(p + 0, v.x);
  atomicAdd(p + 1, v.y);
  atomicAdd(p + 2, v.z);
  atomicAdd(p + 3, v.w);
}

// ---------------- weight transpose 128x128: outT[k][h] = in[h][k] ----------------
__global__ __launch_bounds__(256) void transpose_kernel(const float* __restrict__ in,
                                                        float* __restrict__ outT) {
  int t = blockIdx.x * 256 + threadIdx.x;
  int h = t >> 7, k = t & 127;
  outT[k * 128 + h] = in[h * 128 + k];
}

// ---------------- SAGE conv: out = relu((agg/deg)@wl^T + bl + x@wr^T) ----------------
// wlT/wrT are [k][h] transposed. out may alias agg (block owns its rows).
__global__ __launch_bounds__(256) void conv_kernel(
    const float* __restrict__ xln, const float* __restrict__ agg,
    const float* __restrict__ deg, const float* __restrict__ wlT,
    const float* __restrict__ bl, const float* __restrict__ wrT,
    float* __restrict__ out) {
  __shared__ float Xs[64][68];   // [k][node], pad 68 (2-way write conflict = free)
  __shared__ float Ws[64][132];  // [k][h], 16B-aligned rows
  int tid = threadIdx.x;
  int tx = tid & 31;  // h quad: h = tx*4 .. tx*4+3
  int ty = tid >> 5;  // node octet: nodes ty*8 .. ty*8+7
  int nbase = blockIdx.x * 64;

  float4 acc[8];
#pragma unroll
  for (int m = 0; m < 8; ++m) acc[m] = make_float4(0.f, 0.f, 0.f, 0.f);

  // per-thread staging coords (reused across ks-steps)
  int snn = threadIdx.x & 15;         // node within 16-group
  int skq = threadIdx.x >> 4;         // k-quad 0..15

  for (int ks = 0; ks < 4; ++ks) {
    const float* xsrc = (ks < 2) ? agg : xln;
    const float* wT = (ks < 2) ? wlT : wrT;
    int k0 = (ks & 1) * 64;

    // stage X tile: 64 nodes x 64 k (transposed into LDS)
#pragma unroll
    for (int p = 0; p < 4; ++p) {
      int nn = p * 16 + snn;
      int gn = nbase + nn;
      float4 v = make_float4(0.f, 0.f, 0.f, 0.f);
      if (gn < NN) {
        v = *(const float4*)(xsrc + (size_t)gn * DIM + k0 + skq * 4);
        if (ks < 2) {
          float sc = 1.0f / fmaxf(deg[gn], 1.0f);
          v.x *= sc; v.y *= sc; v.z *= sc; v.w *= sc;
        }
      }
      Xs[skq * 4 + 0][nn] = v.x;
      Xs[skq * 4 + 1][nn] = v.y;
      Xs[skq * 4 + 2][nn] = v.z;
      Xs[skq * 4 + 3][nn] = v.w;
    }
    // stage W tile: 64 k x 128 h
#pragma unroll
    for (int p = 0; p < 8; ++p) {
      int kr = p * 8 + (tid >> 5);
      float4 w = *(const float4*)(wT + (size_t)(k0 + kr) * 128 + (tid & 31) * 4);
      *(float4*)&Ws[kr][(tid & 31) * 4] = w;
    }
    __syncthreads();

#pragma unroll 4
    for (int k = 0; k < 64; ++k) {
      float4 w = *(const float4*)&Ws[k][tx * 4];
      float4 a0 = *(const float4*)&Xs[k][ty * 8];
      float4 a1 = *(const float4*)&Xs[k][ty * 8 + 4];
      float a[8] = {a0.x, a0.y, a0.z, a0.w, a1.x, a1.y, a1.z, a1.w};
#pragma unroll
      for (int m = 0; m < 8; ++m) {
        acc[m].x += a[m] * w.x;
        acc[m].y += a[m] * w.y;
        acc[m].z += a[m] * w.z;
        acc[m].w += a[m] * w.w;
      }
    }
    __syncthreads();
  }

  float4 bias = *(const float4*)(bl + tx * 4);
#pragma unroll
  for (int m = 0; m < 8; ++m) {
    int gn = nbase + ty * 8 + m;
    if (gn < NN) {
      float4 o;
      o.x = fmaxf(acc[m].x + bias.x, 0.f);
      o.y = fmaxf(acc[m].y + bias.y, 0.f);
      o.z = fmaxf(acc[m].z + bias.z, 0.f);
      o.w = fmaxf(acc[m].w + bias.w, 0.f);
      *(float4*)(out + (size_t)gn * DIM + tx * 4) = o;
    }
  }
}

// ---------------- mean pool over sorted batch (run-length compaction) ----------------
#define PCHUNK 128
__global__ __launch_bounds__(128) void pool_kernel(const float* __restrict__ x,
                                                   const int* __restrict__ batch,
                                                   float* __restrict__ pool,
                                                   float* __restrict__ cnt) {
  int f = threadIdx.x;
  int n0 = blockIdx.x * PCHUNK;
  float acc = 0.f;
  int cur = batch[n0];
  int runlen = 0;
  for (int i = 0; i < PCHUNK; ++i) {
    int n = n0 + i;
    if (n >= NN) break;
    int bg = batch[n];
    if (bg != cur) {
      atomicAdd(&pool[cur * DIM + f], acc);
      if (f == 0) atomicAdd(&cnt[cur], (float)runlen);
      acc = 0.f;
      runlen = 0;
      cur = bg;
    }
    acc += x[(size_t)n * DIM + f];
    runlen++;
  }
  if (runlen > 0) {
    atomicAdd(&pool[cur * DIM + f], acc);
    if (f == 0) atomicAdd(&cnt[cur], (float)runlen);
  }
}

// ---------------- MLP head ----------------
__global__ __launch_bounds__(128) void head_kernel(
    const float* __restrict__ pool, const float* __restrict__ cnt,
    const float* __restrict__ w1, const float* __restrict__ b1,
    const float* __restrict__ w2, const float* __restrict__ b2,
    float* __restrict__ out) {
  __shared__ float gsh[128];
  __shared__ float h[64];
  int g = blockIdx.x;
  int t = threadIdx.x;
  float ic = 1.0f / fmaxf(cnt[g], 1.0f);
  gsh[t] = pool[g * DIM + t] * ic;
  __syncthreads();
  if (t < 64) {
    float a = b1[t];
#pragma unroll 8
    for (int k = 0; k < 128; ++k) a += gsh[k] * w1[t * 128 + k];
    h[t] = fmaxf(a, 0.f);
  }
  __syncthreads();
  if (t < 2) {
    float a = b2[t];
#pragma unroll
    for (int k = 0; k < 64; ++k) a += h[k] * w2[t * 64 + k];
    out[g * 2 + t] = a;
  }
}

extern "C" void kernel_launch(void* const* d_in, const int* in_sizes, int n_in,
                              void* d_out, int out_size, void* d_ws, size_t ws_size,
                              hipStream_t stream) {
  const int* x_idx = (const int*)d_in[0];
  const int* eidx = (const int*)d_in[1];
  const int* batch = (const int*)d_in[2];
  const float* emb = (const float*)d_in[3];
  const float* ln0g = (const float*)d_in[4];
  const float* ln0b = (const float*)d_in[5];
  const float* w0l = (const float*)d_in[6];
  const float* b0l = (const float*)d_in[7];
  const float* w0r = (const float*)d_in[8];
  const float* ln1g = (const float*)d_in[9];
  const float* ln1b = (const float*)d_in[10];
  const float* w1l = (const float*)d_in[11];
  const float* b1l = (const float*)d_in[12];
  const float* w1r = (const float*)d_in[13];
  const float* mw1 = (const float*)d_in[14];
  const float* mb1 = (const float*)d_in[15];
  const float* mw2 = (const float*)d_in[16];
  const float* mb2 = (const float*)d_in[17];
  float* out = (float*)d_out;

  float* ws = (float*)d_ws;
  float* x = ws;                               // N*128
  float* agg = x + (size_t)NN * DIM;           // N*128
  float* deg = agg + (size_t)NN * DIM;         // N
  float* pool = deg + NN;                      // G*128
  float* cnt = pool + (size_t)NG * DIM;        // G
  float* w0lT = cnt + NG;                      // 16384
  float* w0rT = w0lT + 16384;
  float* w1lT = w0rT + 16384;
  float* w1rT = w1lT + 16384;

  const int* src = eidx;
  const int* dst = eidx + NE;

  // zero agg, deg, pool, cnt (contiguous)
  size_t zbytes = ((size_t)NN * DIM + NN + (size_t)NG * DIM + NG) * sizeof(float);
  hipMemsetAsync(agg, 0, zbytes, stream);

  transpose_kernel<<<64, 256, 0, stream>>>(w0l, w0lT);
  transpose_kernel<<<64, 256, 0, stream>>>(w0r, w0rT);
  transpose_kernel<<<64, 256, 0, stream>>>(w1l, w1lT);
  transpose_kernel<<<64, 256, 0, stream>>>(w1r, w1rT);

  embed_ln_kernel<<<NN / 4, 256, 0, stream>>>(x_idx, emb, ln0g, ln0b, x);
  deg_kernel<<<(NE + 255) / 256, 256, 0, stream>>>(dst, deg);
  scatter_kernel<<<(NE * 32 + 255) / 256, 256, 0, stream>>>(src, dst, x, agg);
  conv_kernel<<<(NN + 63) / 64, 256, 0, stream>>>(x, agg, deg, w0lT, b0l, w0rT, agg);
  ln_kernel<<<NN / 4, 256, 0, stream>>>(agg, ln1g, ln1b, x);
  hipMemsetAsync(agg, 0, (size_t)NN * DIM * sizeof(float), stream);
  scatter_kernel<<<(NE * 32 + 255) / 256, 256, 0, stream>>>(src, dst, x, agg);
  conv_kernel<<<(NN + 63) / 64, 256, 0, stream>>>(x, agg, deg, w1lT, b1l, w1rT, agg);
  pool_kernel<<<(NN + PCHUNK - 1) / PCHUNK, 128, 0, stream>>>(agg, batch, pool, cnt);
  head_kernel<<<NG, 128, 0, stream>>>(pool, cnt, mw1, mb1, mw2, mb2, out);
}

// Round 4
// 543.018 us; speedup vs baseline: 4.5158x; 4.5158x over previous
//
#include <hip/hip_runtime.h>

#define NN 100000
#define NE 600000
#define DIM 128
#define NG 256
#define NB_SCAN 391  // ceil(NN/256)

// ---------------- embed + layernorm (wave per node) ----------------
__global__ __launch_bounds__(256) void embed_ln_kernel(
    const int* __restrict__ x_idx, const float* __restrict__ emb,
    const float* __restrict__ g, const float* __restrict__ b,
    float* __restrict__ out) {
  int wave = threadIdx.x >> 6;
  int lane = threadIdx.x & 63;
  int n = blockIdx.x * 4 + wave;
  if (n >= NN) return;
  int idx = x_idx[n];
  float2 v = ((const float2*)(emb + (size_t)idx * DIM))[lane];
  float s = v.x + v.y;
  float sq = v.x * v.x + v.y * v.y;
  for (int off = 32; off; off >>= 1) {
    s += __shfl_xor(s, off);
    sq += __shfl_xor(sq, off);
  }
  float m = s * (1.0f / 128.0f);
  float var = sq * (1.0f / 128.0f) - m * m;
  float r = rsqrtf(var + 1e-5f);
  float2 gg = ((const float2*)g)[lane];
  float2 bb = ((const float2*)b)[lane];
  float2 o;
  o.x = (v.x - m) * r * gg.x + bb.x;
  o.y = (v.y - m) * r * gg.y + bb.y;
  ((float2*)(out + (size_t)n * DIM))[lane] = o;
}

// ---------------- layernorm from buffer ----------------
__global__ __launch_bounds__(256) void ln_kernel(
    const float* __restrict__ in, const float* __restrict__ g,
    const float* __restrict__ b, float* __restrict__ out) {
  int wave = threadIdx.x >> 6;
  int lane = threadIdx.x & 63;
  int n = blockIdx.x * 4 + wave;
  if (n >= NN) return;
  float2 v = ((const float2*)(in + (size_t)n * DIM))[lane];
  float s = v.x + v.y;
  float sq = v.x * v.x + v.y * v.y;
  for (int off = 32; off; off >>= 1) {
    s += __shfl_xor(s, off);
    sq += __shfl_xor(sq, off);
  }
  float m = s * (1.0f / 128.0f);
  float var = sq * (1.0f / 128.0f) - m * m;
  float r = rsqrtf(var + 1e-5f);
  float2 gg = ((const float2*)g)[lane];
  float2 bb = ((const float2*)b)[lane];
  float2 o;
  o.x = (v.x - m) * r * gg.x + bb.x;
  o.y = (v.y - m) * r * gg.y + bb.y;
  ((float2*)(out + (size_t)n * DIM))[lane] = o;
}

// ---------------- CSR build ----------------
__global__ __launch_bounds__(256) void deg_int_kernel(const int* __restrict__ dst,
                                                      int* __restrict__ degi) {
  int e = blockIdx.x * 256 + threadIdx.x;
  if (e < NE) atomicAdd(degi + dst[e], 1);
}

__global__ __launch_bounds__(256) void scan1_kernel(const int* __restrict__ degi,
                                                    int* __restrict__ excl,
                                                    int* __restrict__ bsum) {
  __shared__ int tmp[256];
  int t = threadIdx.x;
  int i = blockIdx.x * 256 + t;
  int v = (i < NN) ? degi[i] : 0;
  int val = v;
  tmp[t] = val;
  __syncthreads();
  for (int off = 1; off < 256; off <<= 1) {
    int add = (t >= off) ? tmp[t - off] : 0;
    __syncthreads();
    val += add;
    tmp[t] = val;
    __syncthreads();
  }
  if (i < NN) excl[i] = val - v;
  if (t == 255) bsum[blockIdx.x] = val;
}

__global__ __launch_bounds__(512) void scan2_kernel(int* __restrict__ bsum,
                                                    int* __restrict__ bscan) {
  __shared__ int tmp[512];
  int t = threadIdx.x;
  int v = (t < NB_SCAN) ? bsum[t] : 0;
  int val = v;
  tmp[t] = val;
  __syncthreads();
  for (int off = 1; off < 512; off <<= 1) {
    int add = (t >= off) ? tmp[t - off] : 0;
    __syncthreads();
    val += add;
    tmp[t] = val;
    __syncthreads();
  }
  if (t < NB_SCAN) bscan[t] = val - v;
}

// row_off[i] = excl[i] + bscan[blk]; also init cursor; row_off[NN] = NE
__global__ __launch_bounds__(256) void scan3_kernel(const int* __restrict__ excl,
                                                    const int* __restrict__ bscan,
                                                    int* __restrict__ row_off,
                                                    int* __restrict__ cursor) {
  int i = blockIdx.x * 256 + threadIdx.x;
  if (i < NN) {
    int r = excl[i] + bscan[i >> 8];
    row_off[i] = r;
    cursor[i] = r;
  }
  if (i == 0) row_off[NN] = NE;
}

__global__ __launch_bounds__(256) void fill_kernel(const int* __restrict__ src,
                                                   const int* __restrict__ dst,
                                                   int* __restrict__ cursor,
                                                   int* __restrict__ csr_src) {
  int e = blockIdx.x * 256 + threadIdx.x;
  if (e < NE) {
    int d = dst[e];
    int slot = atomicAdd(cursor + d, 1);
    csr_src[slot] = src[e];
  }
}

// ---------------- gather mean: agg[n] = mean_{e in csr[n]} x[csr_src[e]] ----------------
__global__ __launch_bounds__(256) void gather_mean_kernel(
    const int* __restrict__ row_off, const int* __restrict__ csr_src,
    const float* __restrict__ x, float* __restrict__ agg) {
  int t = threadIdx.x;
  int q = t & 31;                      // float4 slot in feature dim
  int node = blockIdx.x * 8 + (t >> 5);
  if (node >= NN) return;
  int beg = row_off[node], end = row_off[node + 1];
  float4 acc = make_float4(0.f, 0.f, 0.f, 0.f);
  for (int e = beg; e < end; ++e) {
    int s = csr_src[e];
    float4 v = ((const float4*)(x + (size_t)s * DIM))[q];
    acc.x += v.x; acc.y += v.y; acc.z += v.z; acc.w += v.w;
  }
  float sc = 1.0f / fmaxf((float)(end - beg), 1.0f);
  acc.x *= sc; acc.y *= sc; acc.z *= sc; acc.w *= sc;
  ((float4*)(agg + (size_t)node * DIM))[q] = acc;
}

// ---------------- weight transpose 128x128 ----------------
__global__ __launch_bounds__(256) void transpose_kernel(const float* __restrict__ in,
                                                        float* __restrict__ outT) {
  int t = blockIdx.x * 256 + threadIdx.x;
  int h = t >> 7, k = t & 127;
  outT[k * 128 + h] = in[h * 128 + k];
}

// ---------------- SAGE conv: out = relu(agg@wl^T + bl + x@wr^T) ----------------
// agg already contains the mean. out may alias agg (block owns its rows).
__global__ __launch_bounds__(256) void conv_kernel(
    const float* __restrict__ xln, const float* __restrict__ agg,
    const float* __restrict__ wlT, const float* __restrict__ bl,
    const float* __restrict__ wrT, float* __restrict__ out) {
  __shared__ float Xs[64][68];
  __shared__ float Ws[64][132];
  int tid = threadIdx.x;
  int tx = tid & 31;
  int ty = tid >> 5;
  int nbase = blockIdx.x * 64;

  float4 acc[8];
#pragma unroll
  for (int m = 0; m < 8; ++m) acc[m] = make_float4(0.f, 0.f, 0.f, 0.f);

  int snn = tid & 15;
  int skq = tid >> 4;

  for (int ks = 0; ks < 4; ++ks) {
    const float* xsrc = (ks < 2) ? agg : xln;
    const float* wT = (ks < 2) ? wlT : wrT;
    int k0 = (ks & 1) * 64;

#pragma unroll
    for (int p = 0; p < 4; ++p) {
      int nn = p * 16 + snn;
      int gn = nbase + nn;
      float4 v = make_float4(0.f, 0.f, 0.f, 0.f);
      if (gn < NN) v = *(const float4*)(xsrc + (size_t)gn * DIM + k0 + skq * 4);
      Xs[skq * 4 + 0][nn] = v.x;
      Xs[skq * 4 + 1][nn] = v.y;
      Xs[skq * 4 + 2][nn] = v.z;
      Xs[skq * 4 + 3][nn] = v.w;
    }
#pragma unroll
    for (int p = 0; p < 8; ++p) {
      int kr = p * 8 + (tid >> 5);
      float4 w = *(const float4*)(wT + (size_t)(k0 + kr) * 128 + (tid & 31) * 4);
      *(float4*)&Ws[kr][(tid & 31) * 4] = w;
    }
    __syncthreads();

#pragma unroll 4
    for (int k = 0; k < 64; ++k) {
      float4 w = *(const float4*)&Ws[k][tx * 4];
      float4 a0 = *(const float4*)&Xs[k][ty * 8];
      float4 a1 = *(const float4*)&Xs[k][ty * 8 + 4];
      float a[8] = {a0.x, a0.y, a0.z, a0.w, a1.x, a1.y, a1.z, a1.w};
#pragma unroll
      for (int m = 0; m < 8; ++m) {
        acc[m].x += a[m] * w.x;
        acc[m].y += a[m] * w.y;
        acc[m].z += a[m] * w.z;
        acc[m].w += a[m] * w.w;
      }
    }
    __syncthreads();
  }

  float4 bias = *(const float4*)(bl + tx * 4);
#pragma unroll
  for (int m = 0; m < 8; ++m) {
    int gn = nbase + ty * 8 + m;
    if (gn < NN) {
      float4 o;
      o.x = fmaxf(acc[m].x + bias.x, 0.f);
      o.y = fmaxf(acc[m].y + bias.y, 0.f);
      o.z = fmaxf(acc[m].z + bias.z, 0.f);
      o.w = fmaxf(acc[m].w + bias.w, 0.f);
      *(float4*)(out + (size_t)gn * DIM + tx * 4) = o;
    }
  }
}

// ---------------- mean pool over sorted batch ----------------
#define PCHUNK 128
__global__ __launch_bounds__(128) void pool_kernel(const float* __restrict__ x,
                                                   const int* __restrict__ batch,
                                                   float* __restrict__ pool,
                                                   float* __restrict__ cnt) {
  int f = threadIdx.x;
  int n0 = blockIdx.x * PCHUNK;
  float acc = 0.f;
  int cur = batch[n0];
  int runlen = 0;
  for (int i = 0; i < PCHUNK; ++i) {
    int n = n0 + i;
    if (n >= NN) break;
    int bg = batch[n];
    if (bg != cur) {
      atomicAdd(&pool[cur * DIM + f], acc);
      if (f == 0) atomicAdd(&cnt[cur], (float)runlen);
      acc = 0.f;
      runlen = 0;
      cur = bg;
    }
    acc += x[(size_t)n * DIM + f];
    runlen++;
  }
  if (runlen > 0) {
    atomicAdd(&pool[cur * DIM + f], acc);
    if (f == 0) atomicAdd(&cnt[cur], (float)runlen);
  }
}

// ---------------- MLP head ----------------
__global__ __launch_bounds__(128) void head_kernel(
    const float* __restrict__ pool, const float* __restrict__ cnt,
    const float* __restrict__ w1, const float* __restrict__ b1,
    const float* __restrict__ w2, const float* __restrict__ b2,
    float* __restrict__ out) {
  __shared__ float gsh[128];
  __shared__ float h[64];
  int g = blockIdx.x;
  int t = threadIdx.x;
  float ic = 1.0f / fmaxf(cnt[g], 1.0f);
  gsh[t] = pool[g * DIM + t] * ic;
  __syncthreads();
  if (t < 64) {
    float a = b1[t];
#pragma unroll 8
    for (int k = 0; k < 128; ++k) a += gsh[k] * w1[t * 128 + k];
    h[t] = fmaxf(a, 0.f);
  }
  __syncthreads();
  if (t < 2) {
    float a = b2[t];
#pragma unroll
    for (int k = 0; k < 64; ++k) a += h[k] * w2[t * 64 + k];
    out[g * 2 + t] = a;
  }
}

extern "C" void kernel_launch(void* const* d_in, const int* in_sizes, int n_in,
                              void* d_out, int out_size, void* d_ws, size_t ws_size,
                              hipStream_t stream) {
  const int* x_idx = (const int*)d_in[0];
  const int* eidx = (const int*)d_in[1];
  const int* batch = (const int*)d_in[2];
  const float* emb = (const float*)d_in[3];
  const float* ln0g = (const float*)d_in[4];
  const float* ln0b = (const float*)d_in[5];
  const float* w0l = (const float*)d_in[6];
  const float* b0l = (const float*)d_in[7];
  const float* w0r = (const float*)d_in[8];
  const float* ln1g = (const float*)d_in[9];
  const float* ln1b = (const float*)d_in[10];
  const float* w1l = (const float*)d_in[11];
  const float* b1l = (const float*)d_in[12];
  const float* w1r = (const float*)d_in[13];
  const float* mw1 = (const float*)d_in[14];
  const float* mb1 = (const float*)d_in[15];
  const float* mw2 = (const float*)d_in[16];
  const float* mb2 = (const float*)d_in[17];
  float* out = (float*)d_out;

  float* ws = (float*)d_ws;
  float* x = ws;                                  // NN*DIM
  float* agg = x + (size_t)NN * DIM;              // NN*DIM
  float* pool = agg + (size_t)NN * DIM;           // NG*DIM
  float* cnt = pool + (size_t)NG * DIM;           // NG
  float* w0lT = cnt + NG;                         // 16384 x4
  float* w0rT = w0lT + 16384;
  float* w1lT = w0rT + 16384;
  float* w1rT = w1lT + 16384;
  int* degi = (int*)(w1rT + 16384);               // NN
  int* excl = degi + NN;                          // NN
  int* row_off = excl + NN;                       // NN+1
  int* cursor = row_off + NN + 1;                 // NN
  int* bsum = cursor + NN;                        // 512
  int* bscan = bsum + 512;                        // 512
  int* csr_src = bscan + 512;                     // NE

  const int* src = eidx;
  const int* dst = eidx + NE;

  // zero: pool+cnt (contig) and degi
  hipMemsetAsync(pool, 0, ((size_t)NG * DIM + NG) * sizeof(float), stream);
  hipMemsetAsync(degi, 0, (size_t)NN * sizeof(int), stream);

  // CSR build (once, reused by both layers)
  deg_int_kernel<<<(NE + 255) / 256, 256, 0, stream>>>(dst, degi);
  scan1_kernel<<<NB_SCAN, 256, 0, stream>>>(degi, excl, bsum);
  scan2_kernel<<<1, 512, 0, stream>>>(bsum, bscan);
  scan3_kernel<<<NB_SCAN, 256, 0, stream>>>(excl, bscan, row_off, cursor);
  fill_kernel<<<(NE + 255) / 256, 256, 0, stream>>>(src, dst, cursor, csr_src);

  transpose_kernel<<<64, 256, 0, stream>>>(w0l, w0lT);
  transpose_kernel<<<64, 256, 0, stream>>>(w0r, w0rT);
  transpose_kernel<<<64, 256, 0, stream>>>(w1l, w1lT);
  transpose_kernel<<<64, 256, 0, stream>>>(w1r, w1rT);

  embed_ln_kernel<<<NN / 4, 256, 0, stream>>>(x_idx, emb, ln0g, ln0b, x);

  // layer 0
  gather_mean_kernel<<<(NN + 7) / 8, 256, 0, stream>>>(row_off, csr_src, x, agg);
  conv_kernel<<<(NN + 63) / 64, 256, 0, stream>>>(x, agg, w0lT, b0l, w0rT, agg);
  // layer 1
  ln_kernel<<<NN / 4, 256, 0, stream>>>(agg, ln1g, ln1b, x);
  gather_mean_kernel<<<(NN + 7) / 8, 256, 0, stream>>>(row_off, csr_src, x, agg);
  conv_kernel<<<(NN + 63) / 64, 256, 0, stream>>>(x, agg, w1lT, b1l, w1rT, agg);

  pool_kernel<<<(NN + PCHUNK - 1) / PCHUNK, 128, 0, stream>>>(agg, batch, pool, cnt);
  head_kernel<<<NG, 128, 0, stream>>>(pool, cnt, mw1, mb1, mw2, mb2, out);
}